// Round 5
// baseline (403.211 us; speedup 1.0000x reference)
//
#include <hip/hip_runtime.h>

#define VOCAB 50000
#define VDIM 256
#define TOPICS 512
#define VT 32
#define NBLK 1563   // ceil(VOCAB/VT)

typedef unsigned int uint;
typedef unsigned short ushort;
using short8 = __attribute__((ext_vector_type(8))) short;
using f32x4  = __attribute__((ext_vector_type(4))) float;

__device__ __forceinline__ ushort bf16_rne(float f) {
  uint u = __float_as_uint(f);
  u += 0x7FFFu + ((u >> 16) & 1u);
  return (ushort)(u >> 16);
}
__device__ __forceinline__ float bf16f(ushort h) {
  return __uint_as_float(((uint)h) << 16);
}
__device__ __forceinline__ uint packbf2(float a, float b) {
  return (uint)bf16_rne(a) | ((uint)bf16_rne(b) << 16);
}

// ---------------------------------------------------------------------------
// Precompute with fragment-major packing (hi/lo bf16 split):
//   tBp[tile=t>>4][ks=d>>5][hl][lane=(t&15)|(((d>>3)&3)<<4)][e=d&7]
//   Atp[dtile=d>>4][ks=t>>5][hl][lane=(d&15)|(((t>>3)&3)<<4)][e=t&7]
// ---------------------------------------------------------------------------
__global__ __launch_bounds__(512) void precompute(
    const float* __restrict__ t2v, const float* __restrict__ A,
    const float* __restrict__ B,
    ushort* __restrict__ tBp, ushort* __restrict__ Atp)
{
  __shared__ float row[256];
  const int b = blockIdx.x, tid = threadIdx.x;
  if (b < TOPICS) {
    const int t = b;
    if (tid < 256) row[tid] = t2v[(size_t)t * 256 + tid];
    __syncthreads();
    if (tid < 256) {
      const int d = tid;
      const float4* rv = (const float4*)row;
      const float4* bv = (const float4*)(B + (size_t)d * 256);
      float acc = 0.f;
#pragma unroll 8
      for (int k = 0; k < 64; ++k) {
        float4 r = rv[k], x = bv[k];
        acc += r.x * x.x + r.y * x.y + r.z * x.z + r.w * x.w;
      }
      ushort hi = bf16_rne(acc);
      ushort lo = bf16_rne(acc - bf16f(hi));
      const int tile = t >> 4, ks = d >> 5;
      const int lane = (t & 15) | (((d >> 3) & 3) << 4);
      const int e = d & 7;
      size_t base = ((size_t)(tile * 8 + ks) * 2) * 512 + lane * 8 + e;
      tBp[base]       = hi;
      tBp[base + 512] = lo;
    }
  } else {
    const int d = b - TOPICS;
    if (tid < 256) row[tid] = A[(size_t)d * 256 + tid];
    __syncthreads();
    const int t = tid;
    const float4* rv = (const float4*)row;
    const float4* tv = (const float4*)(t2v + (size_t)t * 256);
    float acc = 0.f;
#pragma unroll 8
    for (int k = 0; k < 64; ++k) {
      float4 r = rv[k], x = tv[k];
      acc += r.x * x.x + r.y * x.y + r.z * x.z + r.w * x.w;
    }
    ushort hi = bf16_rne(acc);
    ushort lo = bf16_rne(acc - bf16f(hi));
    const int dtile = d >> 4, ks = t >> 5;
    const int lane = (d & 15) | (((t >> 3) & 3) << 4);
    const int e = t & 7;
    size_t base = ((size_t)(dtile * 16 + ks) * 2) * 512 + lane * 8 + e;
    Atp[base]       = hi;
    Atp[base + 512] = lo;
  }
}

// ---------------------------------------------------------------------------
// Fused main. 4 waves, VT=32 vocab cols.
//  - depth-4 A-fragment register rings in both GEMMs (cover ~L2 latency)
//  - B-frags double-buffered one full K-step ahead
//  - raw s kept in registers all kernel; PA = UNNORMALIZED exp; all global
//    stores after the last barrier
//  - RL partials: part_rs[blk][512] CONTIGUOUS (no partial-line RFO),
//    part_ss[blk*4+wave]
// ---------------------------------------------------------------------------
__global__ __launch_bounds__(256, 4) void fused_main(
    const float* __restrict__ w2v,
    const ushort* __restrict__ tBp, const ushort* __restrict__ Atp,
    const float* __restrict__ sigma,
    float* __restrict__ out_alpha, float* __restrict__ out_P,
    float* __restrict__ out_s,
    float* __restrict__ part_rs, float* __restrict__ part_ss, int do_rl)
{
  __shared__ __align__(16) char smem[33792];
  ushort (*Whi)[264] = (ushort (*)[264])smem;            // 16896 B
  ushort (*Wlo)[264] = (ushort (*)[264])(smem + 16896);  // 16896 B
  ushort (*PA)[520]  = (ushort (*)[520])smem;            // 33280 B (alias, W dead)
  __shared__ float redA[4][VT];
  __shared__ float redB[4][VT];

  const int tid  = threadIdx.x;
  const int wave = tid >> 6, lane = tid & 63;
  const int lr = lane & 15, lg = lane >> 4;
  const int vb = blockIdx.x * VT;

  // ---- issue first 4 A-fragment ring slots before the staging barrier ----
  const ushort* sbase = tBp + (size_t)wave * 65536 + lane * 8;
  short8 Ah[4], Al[4];
#pragma unroll
  for (int i = 0; i < 4; ++i) {
    Ah[i] = *(const short8*)(sbase + (size_t)i * 8192);
    Al[i] = *(const short8*)(sbase + (size_t)i * 8192 + 512);
  }

  // ---- stage W hi/lo ----
#pragma unroll
  for (int it = 0; it < 8; ++it) {
    int j = tid + (it << 8);
    int v = j >> 6, q = j & 63;
    int vr = min(vb + v, VOCAB - 1);
    float4 x = *(const float4*)(w2v + (size_t)vr * 256 + (q << 2));
    float xs[4] = {x.x, x.y, x.z, x.w};
    ushort h[4], l[4];
#pragma unroll
    for (int i = 0; i < 4; ++i) {
      ushort hi = bf16_rne(xs[i]);
      h[i] = hi;
      l[i] = bf16_rne(xs[i] - bf16f(hi));
    }
    *(uint2*)&Whi[v][q << 2] = make_uint2((uint)h[0] | ((uint)h[1] << 16),
                                          (uint)h[2] | ((uint)h[3] << 16));
    *(uint2*)&Wlo[v][q << 2] = make_uint2((uint)l[0] | ((uint)l[1] << 16),
                                          (uint)l[2] | ((uint)l[3] << 16));
  }
  __syncthreads();

  // ---- s-GEMM: flattened 64 steps (ks=n>>3, mi=n&7), depth-4 ring ----
  f32x4 acc[8][2];
#pragma unroll
  for (int mi = 0; mi < 8; ++mi)
#pragma unroll
    for (int nj = 0; nj < 2; ++nj) acc[mi][nj] = (f32x4){0.f, 0.f, 0.f, 0.f};

  short8 Bh[2][2], Bl[2][2];
  {
    const int k0 = lg << 3;
    Bh[0][0] = *(const short8*)&Whi[lr][k0];
    Bh[0][1] = *(const short8*)&Whi[16 + lr][k0];
    Bl[0][0] = *(const short8*)&Wlo[lr][k0];
    Bl[0][1] = *(const short8*)&Wlo[16 + lr][k0];
  }

#pragma unroll
  for (int n = 0; n < 64; ++n) {
    const int ks = n >> 3, mi = n & 7, cs = ks & 1;
    if (mi == 0 && ks < 7) {      // B-frags for next ks, one full ks ahead
      const int k0 = ((ks + 1) << 5) + (lg << 3);
      Bh[cs ^ 1][0] = *(const short8*)&Whi[lr][k0];
      Bh[cs ^ 1][1] = *(const short8*)&Whi[16 + lr][k0];
      Bl[cs ^ 1][0] = *(const short8*)&Wlo[lr][k0];
      Bl[cs ^ 1][1] = *(const short8*)&Wlo[16 + lr][k0];
    }
    short8 ah = Ah[n & 3], al = Al[n & 3];
    if (n + 4 < 64) {             // depth-4 ring refill
      const int n4 = n + 4;
      const ushort* p = sbase + (size_t)(n4 & 7) * 8192 + (size_t)(n4 >> 3) * 1024;
      Ah[n & 3] = *(const short8*)p;
      Al[n & 3] = *(const short8*)(p + 512);
    }
#pragma unroll
    for (int nj = 0; nj < 2; ++nj) {
      acc[mi][nj] = __builtin_amdgcn_mfma_f32_16x16x32_bf16(ah, Bh[cs][nj], acc[mi][nj], 0, 0, 0);
      acc[mi][nj] = __builtin_amdgcn_mfma_f32_16x16x32_bf16(al, Bh[cs][nj], acc[mi][nj], 0, 0, 0);
      acc[mi][nj] = __builtin_amdgcn_mfma_f32_16x16x32_bf16(ah, Bl[cs][nj], acc[mi][nj], 0, 0, 0);
    }
  }

  // ---- softmax max reduce (acc stays raw s) ----
  {
    float pm[2] = {-3.4e38f, -3.4e38f};
#pragma unroll
    for (int mi = 0; mi < 8; ++mi)
#pragma unroll
      for (int nj = 0; nj < 2; ++nj)
#pragma unroll
        for (int r = 0; r < 4; ++r) pm[nj] = fmaxf(pm[nj], acc[mi][nj][r]);
#pragma unroll
    for (int nj = 0; nj < 2; ++nj) {
      pm[nj] = fmaxf(pm[nj], __shfl_xor(pm[nj], 16));
      pm[nj] = fmaxf(pm[nj], __shfl_xor(pm[nj], 32));
    }
    if (lg == 0) { redA[wave][lr] = pm[0]; redA[wave][16 + lr] = pm[1]; }
  }
  __syncthreads();   // barrier A

  float gmax[2];
#pragma unroll
  for (int nj = 0; nj < 2; ++nj) {
    const int c = (nj << 4) + lr;
    gmax[nj] = fmaxf(fmaxf(redA[0][c], redA[1][c]), fmaxf(redA[2][c], redA[3][c]));
  }

  // ---- issue first 4 mu A-fragment ring slots (in flight during exp) ----
  const ushort* mbase = Atp + (size_t)wave * 65536 + lane * 8;
  short8 Mh[4], Ml[4];
#pragma unroll
  for (int i = 0; i < 4; ++i) {
    Mh[i] = *(const short8*)(mbase + (size_t)i * 16384);
    Ml[i] = *(const short8*)(mbase + (size_t)i * 16384 + 512);
  }

  // ---- exp pass: PA = bf16(exp(s-gmax)) UNNORMALIZED; sum for inv ----
  float inv[2];
  {
    float ps[2] = {0.f, 0.f};
#pragma unroll
    for (int mi = 0; mi < 8; ++mi) {
      const int tb = (wave << 7) + (mi << 4) + (lg << 2);
#pragma unroll
      for (int nj = 0; nj < 2; ++nj) {
        float e0 = __expf(acc[mi][nj][0] - gmax[nj]);
        float e1 = __expf(acc[mi][nj][1] - gmax[nj]);
        float e2 = __expf(acc[mi][nj][2] - gmax[nj]);
        float e3 = __expf(acc[mi][nj][3] - gmax[nj]);
        ps[nj] += (e0 + e1) + (e2 + e3);
        uint2 pw;
        pw.x = packbf2(e0, e1);
        pw.y = packbf2(e2, e3);
        *(uint2*)&PA[(nj << 4) + lr][tb] = pw;
      }
    }
#pragma unroll
    for (int nj = 0; nj < 2; ++nj) {
      ps[nj] += __shfl_xor(ps[nj], 16);
      ps[nj] += __shfl_xor(ps[nj], 32);
    }
    if (lg == 0) { redB[wave][lr] = ps[0]; redB[wave][16 + lr] = ps[1]; }
  }
  __syncthreads();   // barrier B (PA visible)
#pragma unroll
  for (int nj = 0; nj < 2; ++nj) {
    const int c = (nj << 4) + lr;
    inv[nj] = 1.0f / (redB[0][c] + redB[1][c] + redB[2][c] + redB[3][c]);
  }

  // ---- mu-GEMM: flattened 64 steps (ks=n>>2, mi=n&3), depth-4 ring ----
  f32x4 macc[4][2];
#pragma unroll
  for (int mi = 0; mi < 4; ++mi)
#pragma unroll
    for (int nj = 0; nj < 2; ++nj) macc[mi][nj] = (f32x4){0.f, 0.f, 0.f, 0.f};

  short8 Pb[2][2];
  {
    const int k0 = lg << 3;
    Pb[0][0] = *(const short8*)&PA[lr][k0];
    Pb[0][1] = *(const short8*)&PA[16 + lr][k0];
  }
#pragma unroll
  for (int n = 0; n < 64; ++n) {
    const int ks = n >> 2, mi = n & 3, cs = ks & 1;
    if (mi == 0 && ks < 15) {
      const int k0 = ((ks + 1) << 5) + (lg << 3);
      Pb[cs ^ 1][0] = *(const short8*)&PA[lr][k0];
      Pb[cs ^ 1][1] = *(const short8*)&PA[16 + lr][k0];
    }
    short8 ah = Mh[n & 3], al = Ml[n & 3];
    if (n + 4 < 64) {
      const int n4 = n + 4;
      const ushort* p = mbase + (size_t)(n4 & 3) * 16384 + (size_t)(n4 >> 2) * 1024;
      Mh[n & 3] = *(const short8*)p;
      Ml[n & 3] = *(const short8*)(p + 512);
    }
#pragma unroll
    for (int nj = 0; nj < 2; ++nj) {
      macc[mi][nj] = __builtin_amdgcn_mfma_f32_16x16x32_bf16(ah, Pb[cs][nj], macc[mi][nj], 0, 0, 0);
      macc[mi][nj] = __builtin_amdgcn_mfma_f32_16x16x32_bf16(al, Pb[cs][nj], macc[mi][nj], 0, 0, 0);
    }
  }

  // ---- P: mu = macc*inv; w2v re-read (L2-hot) ----
  {
    float pp[2] = {0.f, 0.f};
#pragma unroll
    for (int mi = 0; mi < 4; ++mi) {
      const int dbase = (wave << 6) + (mi << 4) + (lg << 2);
#pragma unroll
      for (int nj = 0; nj < 2; ++nj) {
        const int vr = min(vb + (nj << 4) + lr, VOCAB - 1);
        float4 w = *(const float4*)(w2v + (size_t)vr * 256 + dbase);
        float d0 = w.x - macc[mi][nj][0] * inv[nj];
        float d1 = w.y - macc[mi][nj][1] * inv[nj];
        float d2 = w.z - macc[mi][nj][2] * inv[nj];
        float d3 = w.w - macc[mi][nj][3] * inv[nj];
        pp[nj] += d0 * d0 + d1 * d1 + d2 * d2 + d3 * d3;
      }
    }
#pragma unroll
    for (int nj = 0; nj < 2; ++nj) {
      pp[nj] += __shfl_xor(pp[nj], 16);
      pp[nj] += __shfl_xor(pp[nj], 32);
    }
    if (lg == 0) { redA[wave][lr] = pp[0]; redA[wave][16 + lr] = pp[1]; }
  }
  __syncthreads();   // barrier C (last barrier; no global stores issued yet)

  if (tid < VT) {
    float sum = redA[0][tid] + redA[1][tid] + redA[2][tid] + redA[3][tid];
    const int v = vb + tid;
    if (v < VOCAB) out_P[v] = sum / sigma[0];
  }

  // ================= all bulk global stores below: no barriers follow ======

  // ---- alpha recompute + stores + RL partials (part_rs CONTIGUOUS) ----
  float ssq = 0.f;
#pragma unroll
  for (int mi = 0; mi < 8; ++mi) {
    const int tb = (wave << 7) + (mi << 4) + (lg << 2);
#pragma unroll
    for (int r = 0; r < 4; ++r) {
      float av[2];
      float rowp = 0.f;
#pragma unroll
      for (int nj = 0; nj < 2; ++nj) {
        float a = __expf(acc[mi][nj][r] - gmax[nj]) * inv[nj];
        av[nj] = a;
        float am = (vb + (nj << 4) + lr < VOCAB) ? a : 0.f;
        rowp += am;
        ssq = fmaf(am, am, ssq);
      }
#pragma unroll
      for (int nj = 0; nj < 2; ++nj) {
        const int v = vb + (nj << 4) + lr;
        if (v < VOCAB) out_alpha[(size_t)(tb + r) * VOCAB + v] = av[nj];
      }
      if (do_rl) {
        rowp += __shfl_xor(rowp, 1);
        rowp += __shfl_xor(rowp, 2);
        rowp += __shfl_xor(rowp, 4);
        rowp += __shfl_xor(rowp, 8);
        if (lr == 0) part_rs[(size_t)blockIdx.x * TOPICS + tb + r] = rowp;
      }
    }
  }

  // ---- s stores (raw acc) ----
#pragma unroll
  for (int mi = 0; mi < 8; ++mi) {
    const int t = (wave << 7) + (mi << 4) + (lg << 2);
#pragma unroll
    for (int nj = 0; nj < 2; ++nj) {
      const int v = vb + (nj << 4) + lr;
      if (v < VOCAB) {
#pragma unroll
        for (int r = 0; r < 4; ++r)
          out_s[(size_t)(t + r) * VOCAB + v] = acc[mi][nj][r];
      }
    }
  }

  if (do_rl) {
    ssq += __shfl_xor(ssq, 1);
    ssq += __shfl_xor(ssq, 2);
    ssq += __shfl_xor(ssq, 4);
    ssq += __shfl_xor(ssq, 8);
    ssq += __shfl_xor(ssq, 16);
    ssq += __shfl_xor(ssq, 32);
    if (lane == 0) part_ss[blockIdx.x * 4 + wave] = ssq;
  }
}

// ---------------------------------------------------------------------------
// RL pass 2: rowsum[t] = sum_blk part_rs[blk][t].
// Grid: 16 blocks; block b owns t in [b*32, b*32+32). Thread (bi=tid>>5,
// tl=tid&31) strides blk by 8; coalesced 128B row segments; LDS combine.
// ---------------------------------------------------------------------------
__global__ __launch_bounds__(256) void rl_pass2(
    const float* __restrict__ part_rs, float* __restrict__ rowsum)
{
  const int t0 = blockIdx.x * 32;
  const int tl = threadIdx.x & 31, bi = threadIdx.x >> 5;
  float s = 0.f;
  for (int blk = bi; blk < NBLK; blk += 8)
    s += part_rs[(size_t)blk * TOPICS + t0 + tl];
  __shared__ float red[8][33];
  red[bi][tl] = s;
  __syncthreads();
  if (threadIdx.x < 32) {
    float sum = 0.f;
#pragma unroll
    for (int i = 0; i < 8; ++i) sum += red[i][threadIdx.x];
    rowsum[t0 + threadIdx.x] = sum;
  }
}

// RL finalize: RL = sum part_ss - sum_t rowsum^2 / VOCAB
__global__ __launch_bounds__(512) void rl_final_new(
    const float* __restrict__ rowsum, const float* __restrict__ part_ss,
    const float* __restrict__ sigma, float* __restrict__ out_RL,
    float* __restrict__ out_sigma)
{
  const int t = threadIdx.x;
  float b = rowsum[t] * rowsum[t];
  float a = 0.f;
  for (int i = t; i < NBLK * 4; i += 512) a += part_ss[i];
  __shared__ float la[8], lb[8];
  const int lane = t & 63, wave = t >> 6;
#pragma unroll
  for (int off = 32; off > 0; off >>= 1) {
    a += __shfl_xor(a, off);
    b += __shfl_xor(b, off);
  }
  if (lane == 0) { la[wave] = a; lb[wave] = b; }
  __syncthreads();
  if (t == 0) {
    float sa = 0.f, sb = 0.f;
#pragma unroll
    for (int w = 0; w < 8; ++w) { sa += la[w]; sb += lb[w]; }
    out_RL[0] = sa - sb / (float)VOCAB;
    out_sigma[0] = sigma[0];
  }
}

// ---------------------------------------------------------------------------
// Fallback (small ws): old alpha re-read path
// ---------------------------------------------------------------------------
__global__ __launch_bounds__(256) void row_reduce(
    const float* __restrict__ alpha, float* __restrict__ rowsum, float* __restrict__ ssum)
{
  const int t = blockIdx.x;
  const float4* base = (const float4*)(alpha + (size_t)t * VOCAB);
  float rs = 0.f, ss = 0.f;
  for (int i = threadIdx.x; i < VOCAB / 4; i += 256) {
    float4 a = base[i];
    rs += a.x + a.y + a.z + a.w;
    ss += a.x * a.x + a.y * a.y + a.z * a.z + a.w * a.w;
  }
  __shared__ float lr[4], ls[4];
  const int lane = threadIdx.x & 63, wave = threadIdx.x >> 6;
#pragma unroll
  for (int off = 32; off > 0; off >>= 1) {
    rs += __shfl_xor(rs, off);
    ss += __shfl_xor(ss, off);
  }
  if (lane == 0) { lr[wave] = rs; ls[wave] = ss; }
  __syncthreads();
  if (threadIdx.x == 0) {
    rowsum[t] = lr[0] + lr[1] + lr[2] + lr[3];
    ssum[t]   = ls[0] + ls[1] + ls[2] + ls[3];
  }
}

__global__ __launch_bounds__(512) void rl_final_old(
    const float* __restrict__ rowsum, const float* __restrict__ ssum,
    const float* __restrict__ sigma, float* __restrict__ out_RL,
    float* __restrict__ out_sigma)
{
  const int t = threadIdx.x;
  float a = ssum[t];
  float b = rowsum[t] * rowsum[t];
  __shared__ float la[8], lb[8];
  const int lane = t & 63, wave = t >> 6;
#pragma unroll
  for (int off = 32; off > 0; off >>= 1) {
    a += __shfl_xor(a, off);
    b += __shfl_xor(b, off);
  }
  if (lane == 0) { la[wave] = a; lb[wave] = b; }
  __syncthreads();
  if (t == 0) {
    float sa = 0.f, sb = 0.f;
#pragma unroll
    for (int w = 0; w < 8; ++w) { sa += la[w]; sb += lb[w]; }
    out_RL[0] = sa - sb / (float)VOCAB;
    out_sigma[0] = sigma[0];
  }
}

extern "C" void kernel_launch(void* const* d_in, const int* in_sizes, int n_in,
                              void* d_out, int out_size, void* d_ws, size_t ws_size,
                              hipStream_t stream) {
  const float* w2v   = (const float*)d_in[0];  // [50000][256]
  const float* t2v   = (const float*)d_in[1];  // [512][256]
  const float* A     = (const float*)d_in[2];  // [256][256]
  const float* B     = (const float*)d_in[3];  // [256][256]
  const float* sigma = (const float*)d_in[4];  // [1]

  float* out       = (float*)d_out;
  float* out_alpha = out;                                  // 25,600,000
  float* out_P     = out + (size_t)TOPICS * VOCAB;         // 50,000
  float* out_RL    = out_P + VOCAB;                        // 1
  float* out_s     = out_RL + 1;                           // 25,600,000
  float* out_sigma = out_s + (size_t)TOPICS * VOCAB;       // 1

  ushort* tBp = (ushort*)d_ws;                             // 262144 ushorts
  ushort* Atp = tBp + (size_t)262144;                      // 262144 ushorts
  float* tail = (float*)(Atp + (size_t)262144);            // after 1 MiB
  // new-path layout
  float* part_rs = tail;                                   // [NBLK][512]
  float* part_ss = part_rs + (size_t)NBLK * TOPICS;        // 1563*4
  float* rowsum  = part_ss + (size_t)NBLK * 4;             // 512
  size_t need = (size_t)(2 * 262144) * 2 +
                ((size_t)NBLK * TOPICS + (size_t)NBLK * 4 + TOPICS) * 4;
  const int do_rl = (ws_size >= need) ? 1 : 0;

  precompute<<<TOPICS + VDIM, 512, 0, stream>>>(t2v, A, B, tBp, Atp);

  fused_main<<<NBLK, 256, 0, stream>>>(w2v, tBp, Atp, sigma,
                                       out_alpha, out_P, out_s,
                                       part_rs, part_ss, do_rl);

  if (do_rl) {
    rl_pass2<<<16, 256, 0, stream>>>(part_rs, rowsum);
    rl_final_new<<<1, 512, 0, stream>>>(rowsum, part_ss, sigma, out_RL, out_sigma);
  } else {
    float* rs_old = tail;
    float* ss_old = rs_old + TOPICS;
    row_reduce<<<TOPICS, 256, 0, stream>>>(out_alpha, rs_old, ss_old);
    rl_final_old<<<1, 512, 0, stream>>>(rs_old, ss_old, sigma, out_RL, out_sigma);
  }
}

// Round 6
// 364.869 us; speedup vs baseline: 1.1051x; 1.1051x over previous
//
#include <hip/hip_runtime.h>

#define VOCAB 50000
#define VDIM 256
#define TOPICS 512
#define VT 32
#define NBLK 1563   // ceil(VOCAB/VT)

typedef unsigned int uint;
typedef unsigned short ushort;
using short8 = __attribute__((ext_vector_type(8))) short;
using f32x4  = __attribute__((ext_vector_type(4))) float;

__device__ __forceinline__ ushort bf16_rne(float f) {
  uint u = __float_as_uint(f);
  u += 0x7FFFu + ((u >> 16) & 1u);
  return (ushort)(u >> 16);
}
__device__ __forceinline__ float bf16f(ushort h) {
  return __uint_as_float(((uint)h) << 16);
}
__device__ __forceinline__ uint packbf2(float a, float b) {
  return (uint)bf16_rne(a) | ((uint)bf16_rne(b) << 16);
}

// ---------------------------------------------------------------------------
// Precompute with fragment-major packing (hi/lo bf16 split):
//   tBp[tile=t>>4][ks=d>>5][hl][lane=(t&15)|(((d>>3)&3)<<4)][e=d&7]
//   Atp[dtile=d>>4][ks=t>>5][hl][lane=(d&15)|(((t>>3)&3)<<4)][e=t&7]
// ---------------------------------------------------------------------------
__global__ __launch_bounds__(512) void precompute(
    const float* __restrict__ t2v, const float* __restrict__ A,
    const float* __restrict__ B,
    ushort* __restrict__ tBp, ushort* __restrict__ Atp)
{
  __shared__ float row[256];
  const int b = blockIdx.x, tid = threadIdx.x;
  if (b < TOPICS) {
    const int t = b;
    if (tid < 256) row[tid] = t2v[(size_t)t * 256 + tid];
    __syncthreads();
    if (tid < 256) {
      const int d = tid;
      const float4* rv = (const float4*)row;
      const float4* bv = (const float4*)(B + (size_t)d * 256);
      float acc = 0.f;
#pragma unroll 8
      for (int k = 0; k < 64; ++k) {
        float4 r = rv[k], x = bv[k];
        acc += r.x * x.x + r.y * x.y + r.z * x.z + r.w * x.w;
      }
      ushort hi = bf16_rne(acc);
      ushort lo = bf16_rne(acc - bf16f(hi));
      const int tile = t >> 4, ks = d >> 5;
      const int lane = (t & 15) | (((d >> 3) & 3) << 4);
      const int e = d & 7;
      size_t base = ((size_t)(tile * 8 + ks) * 2) * 512 + lane * 8 + e;
      tBp[base]       = hi;
      tBp[base + 512] = lo;
    }
  } else {
    const int d = b - TOPICS;
    if (tid < 256) row[tid] = A[(size_t)d * 256 + tid];
    __syncthreads();
    const int t = tid;
    const float4* rv = (const float4*)row;
    const float4* tv = (const float4*)(t2v + (size_t)t * 256);
    float acc = 0.f;
#pragma unroll 8
    for (int k = 0; k < 64; ++k) {
      float4 r = rv[k], x = tv[k];
      acc += r.x * x.x + r.y * x.y + r.z * x.z + r.w * x.w;
    }
    ushort hi = bf16_rne(acc);
    ushort lo = bf16_rne(acc - bf16f(hi));
    const int dtile = d >> 4, ks = t >> 5;
    const int lane = (d & 15) | (((t >> 3) & 3) << 4);
    const int e = t & 7;
    size_t base = ((size_t)(dtile * 16 + ks) * 2) * 512 + lane * 8 + e;
    Atp[base]       = hi;
    Atp[base + 512] = lo;
  }
}

// ---------------------------------------------------------------------------
// Fused main. 4 waves, VT=32 vocab cols. R6 = R4 structure + R5 part_rs fix:
//  - depth-2 (s) / depth-3 (mu) A-fragment register rings  [R4: no spill @84v]
//  - B-frags double-buffered one full K-step ahead
//  - raw s kept in registers; PA = UNNORMALIZED exp; ALL global stores after
//    the last barrier (no vmcnt(0) store drains at barriers)
//  - part_rs[blk][512] contiguous (full-line writes, no RFO)  [R5 fix]
// ---------------------------------------------------------------------------
__global__ __launch_bounds__(256, 3) void fused_main(
    const float* __restrict__ w2v,
    const ushort* __restrict__ tBp, const ushort* __restrict__ Atp,
    const float* __restrict__ sigma,
    float* __restrict__ out_alpha, float* __restrict__ out_P,
    float* __restrict__ out_s,
    float* __restrict__ part_rs, float* __restrict__ part_ss, int do_rl)
{
  __shared__ __align__(16) char smem[33792];
  ushort (*Whi)[264] = (ushort (*)[264])smem;            // 16896 B
  ushort (*Wlo)[264] = (ushort (*)[264])(smem + 16896);  // 16896 B
  ushort (*PA)[520]  = (ushort (*)[520])smem;            // 33280 B (alias, W dead)
  __shared__ float redA[4][VT];
  __shared__ float redB[4][VT];

  const int tid  = threadIdx.x;
  const int wave = tid >> 6, lane = tid & 63;
  const int lr = lane & 15, lg = lane >> 4;
  const int vb = blockIdx.x * VT;

  // ---- issue first A-fragment loads before the staging barrier ----
  const ushort* sbase = tBp + (size_t)wave * 65536 + lane * 8;
  short8 Ah2[2], Al2[2];
  Ah2[0] = *(const short8*)(sbase);
  Al2[0] = *(const short8*)(sbase + 512);
  Ah2[1] = *(const short8*)(sbase + 8192);
  Al2[1] = *(const short8*)(sbase + 8192 + 512);

  // ---- stage W hi/lo ----
#pragma unroll
  for (int it = 0; it < 8; ++it) {
    int j = tid + (it << 8);
    int v = j >> 6, q = j & 63;
    int vr = min(vb + v, VOCAB - 1);
    float4 x = *(const float4*)(w2v + (size_t)vr * 256 + (q << 2));
    float xs[4] = {x.x, x.y, x.z, x.w};
    ushort h[4], l[4];
#pragma unroll
    for (int i = 0; i < 4; ++i) {
      ushort hi = bf16_rne(xs[i]);
      h[i] = hi;
      l[i] = bf16_rne(xs[i] - bf16f(hi));
    }
    *(uint2*)&Whi[v][q << 2] = make_uint2((uint)h[0] | ((uint)h[1] << 16),
                                          (uint)h[2] | ((uint)h[3] << 16));
    *(uint2*)&Wlo[v][q << 2] = make_uint2((uint)l[0] | ((uint)l[1] << 16),
                                          (uint)l[2] | ((uint)l[3] << 16));
  }
  __syncthreads();

  // ---- s-GEMM: flattened 64 steps (ks=n>>3, mi=n&7), depth-2 ring ----
  f32x4 acc[8][2];
#pragma unroll
  for (int mi = 0; mi < 8; ++mi)
#pragma unroll
    for (int nj = 0; nj < 2; ++nj) acc[mi][nj] = (f32x4){0.f, 0.f, 0.f, 0.f};

  short8 Bh[2][2], Bl[2][2];
  {
    const int k0 = lg << 3;
    Bh[0][0] = *(const short8*)&Whi[lr][k0];
    Bh[0][1] = *(const short8*)&Whi[16 + lr][k0];
    Bl[0][0] = *(const short8*)&Wlo[lr][k0];
    Bl[0][1] = *(const short8*)&Wlo[16 + lr][k0];
  }

#pragma unroll
  for (int n = 0; n < 64; ++n) {
    const int ks = n >> 3, mi = n & 7, cs = ks & 1;
    if (mi == 0 && ks < 7) {      // B-frags for next ks, one full ks ahead
      const int k0 = ((ks + 1) << 5) + (lg << 3);
      Bh[cs ^ 1][0] = *(const short8*)&Whi[lr][k0];
      Bh[cs ^ 1][1] = *(const short8*)&Whi[16 + lr][k0];
      Bl[cs ^ 1][0] = *(const short8*)&Wlo[lr][k0];
      Bl[cs ^ 1][1] = *(const short8*)&Wlo[16 + lr][k0];
    }
    short8 ah = Ah2[n & 1], al = Al2[n & 1];
    if (n + 2 < 64) {             // depth-2 ring across ks boundary
      const int n2 = n + 2;
      const ushort* p = sbase + (size_t)(n2 & 7) * 8192 + (size_t)(n2 >> 3) * 1024;
      Ah2[n & 1] = *(const short8*)p;
      Al2[n & 1] = *(const short8*)(p + 512);
    }
#pragma unroll
    for (int nj = 0; nj < 2; ++nj) {
      acc[mi][nj] = __builtin_amdgcn_mfma_f32_16x16x32_bf16(ah, Bh[cs][nj], acc[mi][nj], 0, 0, 0);
      acc[mi][nj] = __builtin_amdgcn_mfma_f32_16x16x32_bf16(al, Bh[cs][nj], acc[mi][nj], 0, 0, 0);
      acc[mi][nj] = __builtin_amdgcn_mfma_f32_16x16x32_bf16(ah, Bl[cs][nj], acc[mi][nj], 0, 0, 0);
    }
  }

  // ---- softmax max reduce (acc stays raw s) ----
  {
    float pm[2] = {-3.4e38f, -3.4e38f};
#pragma unroll
    for (int mi = 0; mi < 8; ++mi)
#pragma unroll
      for (int nj = 0; nj < 2; ++nj)
#pragma unroll
        for (int r = 0; r < 4; ++r) pm[nj] = fmaxf(pm[nj], acc[mi][nj][r]);
#pragma unroll
    for (int nj = 0; nj < 2; ++nj) {
      pm[nj] = fmaxf(pm[nj], __shfl_xor(pm[nj], 16));
      pm[nj] = fmaxf(pm[nj], __shfl_xor(pm[nj], 32));
    }
    if (lg == 0) { redA[wave][lr] = pm[0]; redA[wave][16 + lr] = pm[1]; }
  }
  __syncthreads();   // barrier A (no stores pending)

  float gmax[2];
#pragma unroll
  for (int nj = 0; nj < 2; ++nj) {
    const int c = (nj << 4) + lr;
    gmax[nj] = fmaxf(fmaxf(redA[0][c], redA[1][c]), fmaxf(redA[2][c], redA[3][c]));
  }

  // ---- issue first 3 mu A-fragment ring slots (in flight during exp) ----
  const ushort* mbase = Atp + (size_t)wave * 65536 + lane * 8;
  short8 Mh[3], Ml[3];
  Mh[0] = *(const short8*)(mbase);
  Ml[0] = *(const short8*)(mbase + 512);
  Mh[1] = *(const short8*)(mbase + 16384);
  Ml[1] = *(const short8*)(mbase + 16384 + 512);
  Mh[2] = *(const short8*)(mbase + 32768);
  Ml[2] = *(const short8*)(mbase + 32768 + 512);

  // ---- exp pass: PA = bf16(exp(s-gmax)) UNNORMALIZED; sum for inv ----
  float inv[2];
  {
    float ps[2] = {0.f, 0.f};
#pragma unroll
    for (int mi = 0; mi < 8; ++mi) {
      const int tb = (wave << 7) + (mi << 4) + (lg << 2);
#pragma unroll
      for (int nj = 0; nj < 2; ++nj) {
        float e0 = __expf(acc[mi][nj][0] - gmax[nj]);
        float e1 = __expf(acc[mi][nj][1] - gmax[nj]);
        float e2 = __expf(acc[mi][nj][2] - gmax[nj]);
        float e3 = __expf(acc[mi][nj][3] - gmax[nj]);
        ps[nj] += (e0 + e1) + (e2 + e3);
        uint2 pw;
        pw.x = packbf2(e0, e1);
        pw.y = packbf2(e2, e3);
        *(uint2*)&PA[(nj << 4) + lr][tb] = pw;
      }
    }
#pragma unroll
    for (int nj = 0; nj < 2; ++nj) {
      ps[nj] += __shfl_xor(ps[nj], 16);
      ps[nj] += __shfl_xor(ps[nj], 32);
    }
    if (lg == 0) { redB[wave][lr] = ps[0]; redB[wave][16 + lr] = ps[1]; }
  }
  __syncthreads();   // barrier B (PA visible; no global stores pending)
#pragma unroll
  for (int nj = 0; nj < 2; ++nj) {
    const int c = (nj << 4) + lr;
    inv[nj] = 1.0f / (redB[0][c] + redB[1][c] + redB[2][c] + redB[3][c]);
  }

  // ---- mu-GEMM: flattened 64 steps (ks=n>>2, mi=n&3), depth-3 ring ----
  f32x4 macc[4][2];
#pragma unroll
  for (int mi = 0; mi < 4; ++mi)
#pragma unroll
    for (int nj = 0; nj < 2; ++nj) macc[mi][nj] = (f32x4){0.f, 0.f, 0.f, 0.f};

  short8 Pb[2][2];
  {
    const int k0 = lg << 3;
    Pb[0][0] = *(const short8*)&PA[lr][k0];
    Pb[0][1] = *(const short8*)&PA[16 + lr][k0];
  }
#pragma unroll
  for (int n = 0; n < 64; ++n) {
    const int ks = n >> 2, mi = n & 3, cs = ks & 1;
    if (mi == 0 && ks < 15) {
      const int k0 = ((ks + 1) << 5) + (lg << 3);
      Pb[cs ^ 1][0] = *(const short8*)&PA[lr][k0];
      Pb[cs ^ 1][1] = *(const short8*)&PA[16 + lr][k0];
    }
    short8 ah = Mh[n % 3], al = Ml[n % 3];
    if (n + 3 < 64) {
      const int n3 = n + 3;
      const ushort* p = mbase + (size_t)(n3 & 3) * 16384 + (size_t)(n3 >> 2) * 1024;
      Mh[n % 3] = *(const short8*)p;
      Ml[n % 3] = *(const short8*)(p + 512);
    }
#pragma unroll
    for (int nj = 0; nj < 2; ++nj) {
      macc[mi][nj] = __builtin_amdgcn_mfma_f32_16x16x32_bf16(ah, Pb[cs][nj], macc[mi][nj], 0, 0, 0);
      macc[mi][nj] = __builtin_amdgcn_mfma_f32_16x16x32_bf16(al, Pb[cs][nj], macc[mi][nj], 0, 0, 0);
    }
  }

  // ---- P: mu = macc*inv; w2v re-read (L2-hot) ----
  {
    float pp[2] = {0.f, 0.f};
#pragma unroll
    for (int mi = 0; mi < 4; ++mi) {
      const int dbase = (wave << 6) + (mi << 4) + (lg << 2);
#pragma unroll
      for (int nj = 0; nj < 2; ++nj) {
        const int vr = min(vb + (nj << 4) + lr, VOCAB - 1);
        float4 w = *(const float4*)(w2v + (size_t)vr * 256 + dbase);
        float d0 = w.x - macc[mi][nj][0] * inv[nj];
        float d1 = w.y - macc[mi][nj][1] * inv[nj];
        float d2 = w.z - macc[mi][nj][2] * inv[nj];
        float d3 = w.w - macc[mi][nj][3] * inv[nj];
        pp[nj] += d0 * d0 + d1 * d1 + d2 * d2 + d3 * d3;
      }
    }
#pragma unroll
    for (int nj = 0; nj < 2; ++nj) {
      pp[nj] += __shfl_xor(pp[nj], 16);
      pp[nj] += __shfl_xor(pp[nj], 32);
    }
    if (lg == 0) { redA[wave][lr] = pp[0]; redA[wave][16 + lr] = pp[1]; }
  }
  __syncthreads();   // barrier C (last barrier; no global stores issued yet)

  if (tid < VT) {
    float sum = redA[0][tid] + redA[1][tid] + redA[2][tid] + redA[3][tid];
    const int v = vb + tid;
    if (v < VOCAB) out_P[v] = sum / sigma[0];
  }

  // ================= all bulk global stores below: no barriers follow ======

  // ---- alpha recompute + stores + RL partials (part_rs CONTIGUOUS) ----
  float ssq = 0.f;
#pragma unroll
  for (int mi = 0; mi < 8; ++mi) {
    const int tb = (wave << 7) + (mi << 4) + (lg << 2);
#pragma unroll
    for (int r = 0; r < 4; ++r) {
      float av[2];
      float rowp = 0.f;
#pragma unroll
      for (int nj = 0; nj < 2; ++nj) {
        float a = __expf(acc[mi][nj][r] - gmax[nj]) * inv[nj];
        av[nj] = a;
        float am = (vb + (nj << 4) + lr < VOCAB) ? a : 0.f;
        rowp += am;
        ssq = fmaf(am, am, ssq);
      }
#pragma unroll
      for (int nj = 0; nj < 2; ++nj) {
        const int v = vb + (nj << 4) + lr;
        if (v < VOCAB) out_alpha[(size_t)(tb + r) * VOCAB + v] = av[nj];
      }
      if (do_rl) {
        rowp += __shfl_xor(rowp, 1);
        rowp += __shfl_xor(rowp, 2);
        rowp += __shfl_xor(rowp, 4);
        rowp += __shfl_xor(rowp, 8);
        if (lr == 0) part_rs[(size_t)blockIdx.x * TOPICS + tb + r] = rowp;
      }
    }
  }

  // ---- s stores (raw acc), 128B line-pair order (r outer, nj inner) ----
#pragma unroll
  for (int mi = 0; mi < 8; ++mi) {
    const int t = (wave << 7) + (mi << 4) + (lg << 2);
#pragma unroll
    for (int r = 0; r < 4; ++r)
#pragma unroll
      for (int nj = 0; nj < 2; ++nj) {
        const int v = vb + (nj << 4) + lr;
        if (v < VOCAB) out_s[(size_t)(t + r) * VOCAB + v] = acc[mi][nj][r];
      }
  }

  if (do_rl) {
    ssq += __shfl_xor(ssq, 1);
    ssq += __shfl_xor(ssq, 2);
    ssq += __shfl_xor(ssq, 4);
    ssq += __shfl_xor(ssq, 8);
    ssq += __shfl_xor(ssq, 16);
    ssq += __shfl_xor(ssq, 32);
    if (lane == 0) part_ss[blockIdx.x * 4 + wave] = ssq;
  }
}

// ---------------------------------------------------------------------------
// RL pass 2: rowsum[t] = sum_blk part_rs[blk][t].
// 16 blocks; block b owns t in [b*32, b*32+32). Coalesced row segments.
// ---------------------------------------------------------------------------
__global__ __launch_bounds__(256) void rl_pass2(
    const float* __restrict__ part_rs, float* __restrict__ rowsum)
{
  const int t0 = blockIdx.x * 32;
  const int tl = threadIdx.x & 31, bi = threadIdx.x >> 5;
  float s = 0.f;
  for (int blk = bi; blk < NBLK; blk += 8)
    s += part_rs[(size_t)blk * TOPICS + t0 + tl];
  __shared__ float red[8][33];
  red[bi][tl] = s;
  __syncthreads();
  if (threadIdx.x < 32) {
    float sum = 0.f;
#pragma unroll
    for (int i = 0; i < 8; ++i) sum += red[i][threadIdx.x];
    rowsum[t0 + threadIdx.x] = sum;
  }
}

// RL finalize: RL = sum part_ss - sum_t rowsum^2 / VOCAB
__global__ __launch_bounds__(512) void rl_final_new(
    const float* __restrict__ rowsum, const float* __restrict__ part_ss,
    const float* __restrict__ sigma, float* __restrict__ out_RL,
    float* __restrict__ out_sigma)
{
  const int t = threadIdx.x;
  float b = rowsum[t] * rowsum[t];
  float a = 0.f;
  for (int i = t; i < NBLK * 4; i += 512) a += part_ss[i];
  __shared__ float la[8], lb[8];
  const int lane = t & 63, wave = t >> 6;
#pragma unroll
  for (int off = 32; off > 0; off >>= 1) {
    a += __shfl_xor(a, off);
    b += __shfl_xor(b, off);
  }
  if (lane == 0) { la[wave] = a; lb[wave] = b; }
  __syncthreads();
  if (t == 0) {
    float sa = 0.f, sb = 0.f;
#pragma unroll
    for (int w = 0; w < 8; ++w) { sa += la[w]; sb += lb[w]; }
    out_RL[0] = sa - sb / (float)VOCAB;
    out_sigma[0] = sigma[0];
  }
}

// ---------------------------------------------------------------------------
// Fallback (small ws): old alpha re-read path
// ---------------------------------------------------------------------------
__global__ __launch_bounds__(256) void row_reduce(
    const float* __restrict__ alpha, float* __restrict__ rowsum, float* __restrict__ ssum)
{
  const int t = blockIdx.x;
  const float4* base = (const float4*)(alpha + (size_t)t * VOCAB);
  float rs = 0.f, ss = 0.f;
  for (int i = threadIdx.x; i < VOCAB / 4; i += 256) {
    float4 a = base[i];
    rs += a.x + a.y + a.z + a.w;
    ss += a.x * a.x + a.y * a.y + a.z * a.z + a.w * a.w;
  }
  __shared__ float lr[4], ls[4];
  const int lane = threadIdx.x & 63, wave = threadIdx.x >> 6;
#pragma unroll
  for (int off = 32; off > 0; off >>= 1) {
    rs += __shfl_xor(rs, off);
    ss += __shfl_xor(ss, off);
  }
  if (lane == 0) { lr[wave] = rs; ls[wave] = ss; }
  __syncthreads();
  if (threadIdx.x == 0) {
    rowsum[t] = lr[0] + lr[1] + lr[2] + lr[3];
    ssum[t]   = ls[0] + ls[1] + ls[2] + ls[3];
  }
}

__global__ __launch_bounds__(512) void rl_final_old(
    const float* __restrict__ rowsum, const float* __restrict__ ssum,
    const float* __restrict__ sigma, float* __restrict__ out_RL,
    float* __restrict__ out_sigma)
{
  const int t = threadIdx.x;
  float a = ssum[t];
  float b = rowsum[t] * rowsum[t];
  __shared__ float la[8], lb[8];
  const int lane = t & 63, wave = t >> 6;
#pragma unroll
  for (int off = 32; off > 0; off >>= 1) {
    a += __shfl_xor(a, off);
    b += __shfl_xor(b, off);
  }
  if (lane == 0) { la[wave] = a; lb[wave] = b; }
  __syncthreads();
  if (t == 0) {
    float sa = 0.f, sb = 0.f;
#pragma unroll
    for (int w = 0; w < 8; ++w) { sa += la[w]; sb += lb[w]; }
    out_RL[0] = sa - sb / (float)VOCAB;
    out_sigma[0] = sigma[0];
  }
}

extern "C" void kernel_launch(void* const* d_in, const int* in_sizes, int n_in,
                              void* d_out, int out_size, void* d_ws, size_t ws_size,
                              hipStream_t stream) {
  const float* w2v   = (const float*)d_in[0];  // [50000][256]
  const float* t2v   = (const float*)d_in[1];  // [512][256]
  const float* A     = (const float*)d_in[2];  // [256][256]
  const float* B     = (const float*)d_in[3];  // [256][256]
  const float* sigma = (const float*)d_in[4];  // [1]

  float* out       = (float*)d_out;
  float* out_alpha = out;                                  // 25,600,000
  float* out_P     = out + (size_t)TOPICS * VOCAB;         // 50,000
  float* out_RL    = out_P + VOCAB;                        // 1
  float* out_s     = out_RL + 1;                           // 25,600,000
  float* out_sigma = out_s + (size_t)TOPICS * VOCAB;       // 1

  ushort* tBp = (ushort*)d_ws;                             // 262144 ushorts
  ushort* Atp = tBp + (size_t)262144;                      // 262144 ushorts
  float* tail = (float*)(Atp + (size_t)262144);            // after 1 MiB
  float* part_rs = tail;                                   // [NBLK][512]
  float* part_ss = part_rs + (size_t)NBLK * TOPICS;        // 1563*4
  float* rowsum  = part_ss + (size_t)NBLK * 4;             // 512
  size_t need = (size_t)(2 * 262144) * 2 +
                ((size_t)NBLK * TOPICS + (size_t)NBLK * 4 + TOPICS) * 4;
  const int do_rl = (ws_size >= need) ? 1 : 0;

  precompute<<<TOPICS + VDIM, 512, 0, stream>>>(t2v, A, B, tBp, Atp);

  fused_main<<<NBLK, 256, 0, stream>>>(w2v, tBp, Atp, sigma,
                                       out_alpha, out_P, out_s,
                                       part_rs, part_ss, do_rl);

  if (do_rl) {
    rl_pass2<<<16, 256, 0, stream>>>(part_rs, rowsum);
    rl_final_new<<<1, 512, 0, stream>>>(rowsum, part_ss, sigma, out_RL, out_sigma);
  } else {
    float* rs_old = tail;
    float* ss_old = rs_old + TOPICS;
    row_reduce<<<TOPICS, 256, 0, stream>>>(out_alpha, rs_old, ss_old);
    rl_final_old<<<1, 512, 0, stream>>>(rs_old, ss_old, sigma, out_RL, out_sigma);
  }
}

// Round 7
// 257.124 us; speedup vs baseline: 1.5682x; 1.4190x over previous
//
#include <hip/hip_runtime.h>

#define VOCAB 50000
#define VDIM 256
#define TOPICS 512
#define VT 32
#define NBLK 1563   // ceil(VOCAB/VT)

typedef unsigned int uint;
typedef unsigned short ushort;
using short8 = __attribute__((ext_vector_type(8))) short;
using f32x4  = __attribute__((ext_vector_type(4))) float;

__device__ __forceinline__ ushort bf16_rne(float f) {
  uint u = __float_as_uint(f);
  u += 0x7FFFu + ((u >> 16) & 1u);
  return (ushort)(u >> 16);
}
__device__ __forceinline__ float bf16f(ushort h) {
  return __uint_as_float(((uint)h) << 16);
}
__device__ __forceinline__ uint packbf2(float a, float b) {
  return (uint)bf16_rne(a) | ((uint)bf16_rne(b) << 16);
}

// ---------------------------------------------------------------------------
// Precompute with fragment-major packing (hi/lo bf16 split):
//   tBp[tile=t>>4][ks=d>>5][hl][lane=(t&15)|(((d>>3)&3)<<4)][e=d&7]
//   Atp[dtile=d>>4][ks=t>>5][hl][lane=(d&15)|(((t>>3)&3)<<4)][e=t&7]
// Each wave-load in fused_main is one coalesced 1KB dwordx4.
// ---------------------------------------------------------------------------
__global__ __launch_bounds__(512) void precompute(
    const float* __restrict__ t2v, const float* __restrict__ A,
    const float* __restrict__ B,
    ushort* __restrict__ tBp, ushort* __restrict__ Atp)
{
  __shared__ float row[256];
  const int b = blockIdx.x, tid = threadIdx.x;
  if (b < TOPICS) {
    const int t = b;
    if (tid < 256) row[tid] = t2v[(size_t)t * 256 + tid];
    __syncthreads();
    if (tid < 256) {
      const int d = tid;
      const float4* rv = (const float4*)row;
      const float4* bv = (const float4*)(B + (size_t)d * 256);
      float acc = 0.f;
#pragma unroll 8
      for (int k = 0; k < 64; ++k) {
        float4 r = rv[k], x = bv[k];
        acc += r.x * x.x + r.y * x.y + r.z * x.z + r.w * x.w;
      }
      ushort hi = bf16_rne(acc);
      ushort lo = bf16_rne(acc - bf16f(hi));
      const int tile = t >> 4, ks = d >> 5;
      const int lane = (t & 15) | (((d >> 3) & 3) << 4);
      const int e = d & 7;
      size_t base = ((size_t)(tile * 8 + ks) * 2) * 512 + lane * 8 + e;
      tBp[base]       = hi;
      tBp[base + 512] = lo;
    }
  } else {
    const int d = b - TOPICS;
    if (tid < 256) row[tid] = A[(size_t)d * 256 + tid];
    __syncthreads();
    const int t = tid;
    const float4* rv = (const float4*)row;
    const float4* tv = (const float4*)(t2v + (size_t)t * 256);
    float acc = 0.f;
#pragma unroll 8
    for (int k = 0; k < 64; ++k) {
      float4 r = rv[k], x = tv[k];
      acc += r.x * x.x + r.y * x.y + r.z * x.z + r.w * x.w;
    }
    ushort hi = bf16_rne(acc);
    ushort lo = bf16_rne(acc - bf16f(hi));
    const int dtile = d >> 4, ks = t >> 5;
    const int lane = (d & 15) | (((t >> 3) & 3) << 4);
    const int e = t & 7;
    size_t base = ((size_t)(dtile * 16 + ks) * 2) * 512 + lane * 8 + e;
    Atp[base]       = hi;
    Atp[base + 512] = lo;
  }
}

// ---------------------------------------------------------------------------
// Fused main — EXACT R3 structure (proven 186 µs: interleaved stores, no
// deferred burst), with ONE addition: RL partials computed in the alpha
// phase (contiguous part_rs[blk][512]) to eliminate the 102 MB alpha
// re-read by row_reduce.
// ---------------------------------------------------------------------------
__global__ __launch_bounds__(256, 4) void fused_main(
    const float* __restrict__ w2v,
    const ushort* __restrict__ tBp, const ushort* __restrict__ Atp,
    const float* __restrict__ sigma,
    float* __restrict__ out_alpha, float* __restrict__ out_P,
    float* __restrict__ out_s,
    float* __restrict__ part_rs, float* __restrict__ part_ss, int do_rl)
{
  __shared__ __align__(16) char smem[33792];
  ushort (*Whi)[264] = (ushort (*)[264])smem;            // 16896 B
  ushort (*Wlo)[264] = (ushort (*)[264])(smem + 16896);  // 16896 B
  ushort (*PA)[520]  = (ushort (*)[520])smem;            // 33280 B (alias, W dead)
  __shared__ float red[4][VT];

  const int tid  = threadIdx.x;
  const int wave = tid >> 6, lane = tid & 63;
  const int lr = lane & 15, lg = lane >> 4;
  const int vb = blockIdx.x * VT;

  // ---- stage W hi/lo (32 rows x 256 dims) ----
#pragma unroll
  for (int it = 0; it < 8; ++it) {
    int j = tid + (it << 8);
    int v = j >> 6, q = j & 63;
    int vr = min(vb + v, VOCAB - 1);
    float4 x = *(const float4*)(w2v + (size_t)vr * 256 + (q << 2));
    float xs[4] = {x.x, x.y, x.z, x.w};
    ushort h[4], l[4];
#pragma unroll
    for (int i = 0; i < 4; ++i) {
      ushort hi = bf16_rne(xs[i]);
      h[i] = hi;
      l[i] = bf16_rne(xs[i] - bf16f(hi));
    }
    *(uint2*)&Whi[v][q << 2] = make_uint2((uint)h[0] | ((uint)h[1] << 16),
                                          (uint)h[2] | ((uint)h[3] << 16));
    *(uint2*)&Wlo[v][q << 2] = make_uint2((uint)l[0] | ((uint)l[1] << 16),
                                          (uint)l[2] | ((uint)l[3] << 16));
  }
  __syncthreads();

  // ---- s-GEMM: acc[mi][nj], t-rows = wave*128 + mi*16 + lr ----
  f32x4 acc[8][2];
#pragma unroll
  for (int mi = 0; mi < 8; ++mi)
#pragma unroll
    for (int nj = 0; nj < 2; ++nj) acc[mi][nj] = (f32x4){0.f, 0.f, 0.f, 0.f};

#pragma unroll
  for (int ks = 0; ks < 8; ++ks) {
    const int k0 = (ks << 5) + (lg << 3);
    short8 bh[2], bl[2];
#pragma unroll
    for (int nj = 0; nj < 2; ++nj) {
      bh[nj] = *(const short8*)&Whi[(nj << 4) + lr][k0];
      bl[nj] = *(const short8*)&Wlo[(nj << 4) + lr][k0];
    }
    // packed A base: tile = wave*8 + mi; stride per tile = 8192 ushorts
    const ushort* abase = tBp + ((size_t)(wave * 8) * 8 + ks) * 1024 + lane * 8;
    short8 ahp[2], alp[2];
    ahp[0] = *(const short8*)(abase);
    alp[0] = *(const short8*)(abase + 512);
    ahp[1] = *(const short8*)(abase + 8192);
    alp[1] = *(const short8*)(abase + 8192 + 512);
#pragma unroll
    for (int mi = 0; mi < 8; ++mi) {
      short8 ah = ahp[mi & 1], al = alp[mi & 1];
      if (mi < 6) {
        ahp[mi & 1] = *(const short8*)(abase + (size_t)(mi + 2) * 8192);
        alp[mi & 1] = *(const short8*)(abase + (size_t)(mi + 2) * 8192 + 512);
      }
#pragma unroll
      for (int nj = 0; nj < 2; ++nj) {
        acc[mi][nj] = __builtin_amdgcn_mfma_f32_16x16x32_bf16(ah, bh[nj], acc[mi][nj], 0, 0, 0);
        acc[mi][nj] = __builtin_amdgcn_mfma_f32_16x16x32_bf16(al, bh[nj], acc[mi][nj], 0, 0, 0);
        acc[mi][nj] = __builtin_amdgcn_mfma_f32_16x16x32_bf16(ah, bl[nj], acc[mi][nj], 0, 0, 0);
      }
    }
  }

  // ---- write s (D layout: col = lr, row = lg*4 + r) ----
#pragma unroll
  for (int mi = 0; mi < 8; ++mi) {
    const int t = (wave << 7) + (mi << 4) + (lg << 2);
#pragma unroll
    for (int r = 0; r < 4; ++r)
#pragma unroll
      for (int nj = 0; nj < 2; ++nj) {
        const int v = vb + (nj << 4) + lr;
        if (v < VOCAB) out_s[(size_t)(t + r) * VOCAB + v] = acc[mi][nj][r];
      }
  }

  // ---- softmax over t per column ----
  float gmax[2];
  {
    float pm[2] = {-3.4e38f, -3.4e38f};
#pragma unroll
    for (int mi = 0; mi < 8; ++mi)
#pragma unroll
      for (int nj = 0; nj < 2; ++nj)
#pragma unroll
        for (int r = 0; r < 4; ++r) pm[nj] = fmaxf(pm[nj], acc[mi][nj][r]);
#pragma unroll
    for (int nj = 0; nj < 2; ++nj) {
      pm[nj] = fmaxf(pm[nj], __shfl_xor(pm[nj], 16));
      pm[nj] = fmaxf(pm[nj], __shfl_xor(pm[nj], 32));
    }
    if (lg == 0) { red[wave][lr] = pm[0]; red[wave][16 + lr] = pm[1]; }
  }
  __syncthreads();
#pragma unroll
  for (int nj = 0; nj < 2; ++nj) {
    const int c = (nj << 4) + lr;
    gmax[nj] = fmaxf(fmaxf(red[0][c], red[1][c]), fmaxf(red[2][c], red[3][c]));
  }
  __syncthreads();

  float inv[2];
  {
    float ps[2] = {0.f, 0.f};
#pragma unroll
    for (int mi = 0; mi < 8; ++mi)
#pragma unroll
      for (int nj = 0; nj < 2; ++nj)
#pragma unroll
        for (int r = 0; r < 4; ++r) {
          float e = __expf(acc[mi][nj][r] - gmax[nj]);
          acc[mi][nj][r] = e;
          ps[nj] += e;
        }
#pragma unroll
    for (int nj = 0; nj < 2; ++nj) {
      ps[nj] += __shfl_xor(ps[nj], 16);
      ps[nj] += __shfl_xor(ps[nj], 32);
    }
    if (lg == 0) { red[wave][lr] = ps[0]; red[wave][16 + lr] = ps[1]; }
  }
  __syncthreads();
#pragma unroll
  for (int nj = 0; nj < 2; ++nj) {
    const int c = (nj << 4) + lr;
    inv[nj] = 1.0f / (red[0][c] + red[1][c] + red[2][c] + red[3][c]);
  }
  __syncthreads();   // red reads done; last Whi/Wlo reads were in s-loop

  // ---- alpha = exp*inv: write fp32 to global, bf16 to LDS (PA aliases W),
  //      plus RL partials (rowsum over this block's 32 cols; sum alpha^2) ----
  float ssq = 0.f;
#pragma unroll
  for (int mi = 0; mi < 8; ++mi) {
    const int tb = (wave << 7) + (mi << 4) + (lg << 2);
#pragma unroll
    for (int nj = 0; nj < 2; ++nj) {
#pragma unroll
      for (int r = 0; r < 4; ++r) acc[mi][nj][r] *= inv[nj];
      const int v = vb + (nj << 4) + lr;
      if (v < VOCAB) {
#pragma unroll
        for (int r = 0; r < 4; ++r)
          out_alpha[(size_t)(tb + r) * VOCAB + v] = acc[mi][nj][r];
      }
      uint2 pw;
      pw.x = packbf2(acc[mi][nj][0], acc[mi][nj][1]);
      pw.y = packbf2(acc[mi][nj][2], acc[mi][nj][3]);
      *(uint2*)&PA[(nj << 4) + lr][tb] = pw;
    }
    if (do_rl) {
#pragma unroll
      for (int r = 0; r < 4; ++r) {
        float rowp = 0.f;
#pragma unroll
        for (int nj = 0; nj < 2; ++nj) {
          float a = acc[mi][nj][r];
          float am = (vb + (nj << 4) + lr < VOCAB) ? a : 0.f;
          rowp += am;
          ssq = fmaf(am, am, ssq);
        }
        rowp += __shfl_xor(rowp, 1);
        rowp += __shfl_xor(rowp, 2);
        rowp += __shfl_xor(rowp, 4);
        rowp += __shfl_xor(rowp, 8);
        if (lr == 0) part_rs[(size_t)blockIdx.x * TOPICS + tb + r] = rowp;
      }
    }
  }
  __syncthreads();

  // ---- mu-GEMM: macc[mi][nj], d-rows = wave*64 + mi*16 + lr, K=512 ----
  f32x4 macc[4][2];
#pragma unroll
  for (int mi = 0; mi < 4; ++mi)
#pragma unroll
    for (int nj = 0; nj < 2; ++nj) macc[mi][nj] = (f32x4){0.f, 0.f, 0.f, 0.f};

#pragma unroll
  for (int ks = 0; ks < 16; ++ks) {
    const int k0 = (ks << 5) + (lg << 3);
    short8 pb[2];
#pragma unroll
    for (int nj = 0; nj < 2; ++nj)
      pb[nj] = *(const short8*)&PA[(nj << 4) + lr][k0];
    // packed At base: dtile = wave*4 + mi; stride per dtile = 16384 ushorts
    const ushort* abase = Atp + ((size_t)(wave * 4) * 16 + ks) * 1024 + lane * 8;
    short8 ahp[2], alp[2];
    ahp[0] = *(const short8*)(abase);
    alp[0] = *(const short8*)(abase + 512);
    ahp[1] = *(const short8*)(abase + 16384);
    alp[1] = *(const short8*)(abase + 16384 + 512);
#pragma unroll
    for (int mi = 0; mi < 4; ++mi) {
      short8 ah = ahp[mi & 1], al = alp[mi & 1];
      if (mi < 2) {
        ahp[mi & 1] = *(const short8*)(abase + (size_t)(mi + 2) * 16384);
        alp[mi & 1] = *(const short8*)(abase + (size_t)(mi + 2) * 16384 + 512);
      }
#pragma unroll
      for (int nj = 0; nj < 2; ++nj) {
        macc[mi][nj] = __builtin_amdgcn_mfma_f32_16x16x32_bf16(ah, pb[nj], macc[mi][nj], 0, 0, 0);
        macc[mi][nj] = __builtin_amdgcn_mfma_f32_16x16x32_bf16(al, pb[nj], macc[mi][nj], 0, 0, 0);
      }
    }
  }

  // ---- P: sum_d (w2v - mu)^2 per column (w2v re-read from global/L2) ----
  {
    float pp[2] = {0.f, 0.f};
#pragma unroll
    for (int mi = 0; mi < 4; ++mi) {
      const int dbase = (wave << 6) + (mi << 4) + (lg << 2);
#pragma unroll
      for (int nj = 0; nj < 2; ++nj) {
        const int vr = min(vb + (nj << 4) + lr, VOCAB - 1);
        float4 w = *(const float4*)(w2v + (size_t)vr * 256 + dbase);
        float d0 = w.x - macc[mi][nj][0];
        float d1 = w.y - macc[mi][nj][1];
        float d2 = w.z - macc[mi][nj][2];
        float d3 = w.w - macc[mi][nj][3];
        pp[nj] += d0 * d0 + d1 * d1 + d2 * d2 + d3 * d3;
      }
    }
#pragma unroll
    for (int nj = 0; nj < 2; ++nj) {
      pp[nj] += __shfl_xor(pp[nj], 16);
      pp[nj] += __shfl_xor(pp[nj], 32);
    }
    if (lg == 0) { red[wave][lr] = pp[0]; red[wave][16 + lr] = pp[1]; }
  }
  __syncthreads();
  if (tid < VT) {
    float sum = red[0][tid] + red[1][tid] + red[2][tid] + red[3][tid];
    const int v = vb + tid;
    if (v < VOCAB) out_P[v] = sum / sigma[0];
  }

  if (do_rl) {
    ssq += __shfl_xor(ssq, 1);
    ssq += __shfl_xor(ssq, 2);
    ssq += __shfl_xor(ssq, 4);
    ssq += __shfl_xor(ssq, 8);
    ssq += __shfl_xor(ssq, 16);
    ssq += __shfl_xor(ssq, 32);
    if (lane == 0) part_ss[blockIdx.x * 4 + wave] = ssq;
  }
}

// ---------------------------------------------------------------------------
// RL pass 2: rowsum[t] = sum_blk part_rs[blk][t]. 16 blocks, coalesced.
// ---------------------------------------------------------------------------
__global__ __launch_bounds__(256) void rl_pass2(
    const float* __restrict__ part_rs, float* __restrict__ rowsum)
{
  const int t0 = blockIdx.x * 32;
  const int tl = threadIdx.x & 31, bi = threadIdx.x >> 5;
  float s = 0.f;
  for (int blk = bi; blk < NBLK; blk += 8)
    s += part_rs[(size_t)blk * TOPICS + t0 + tl];
  __shared__ float red[8][33];
  red[bi][tl] = s;
  __syncthreads();
  if (threadIdx.x < 32) {
    float sum = 0.f;
#pragma unroll
    for (int i = 0; i < 8; ++i) sum += red[i][threadIdx.x];
    rowsum[t0 + threadIdx.x] = sum;
  }
}

// RL finalize: RL = sum part_ss - sum_t rowsum^2 / VOCAB
__global__ __launch_bounds__(512) void rl_final_new(
    const float* __restrict__ rowsum, const float* __restrict__ part_ss,
    const float* __restrict__ sigma, float* __restrict__ out_RL,
    float* __restrict__ out_sigma)
{
  const int t = threadIdx.x;
  float b = rowsum[t] * rowsum[t];
  float a = 0.f;
  for (int i = t; i < NBLK * 4; i += 512) a += part_ss[i];
  __shared__ float la[8], lb[8];
  const int lane = t & 63, wave = t >> 6;
#pragma unroll
  for (int off = 32; off > 0; off >>= 1) {
    a += __shfl_xor(a, off);
    b += __shfl_xor(b, off);
  }
  if (lane == 0) { la[wave] = a; lb[wave] = b; }
  __syncthreads();
  if (t == 0) {
    float sa = 0.f, sb = 0.f;
#pragma unroll
    for (int w = 0; w < 8; ++w) { sa += la[w]; sb += lb[w]; }
    out_RL[0] = sa - sb / (float)VOCAB;
    out_sigma[0] = sigma[0];
  }
}

// ---------------------------------------------------------------------------
// Fallback (small ws): old alpha re-read path
// ---------------------------------------------------------------------------
__global__ __launch_bounds__(256) void row_reduce(
    const float* __restrict__ alpha, float* __restrict__ rowsum, float* __restrict__ ssum)
{
  const int t = blockIdx.x;
  const float4* base = (const float4*)(alpha + (size_t)t * VOCAB);
  float rs = 0.f, ss = 0.f;
  for (int i = threadIdx.x; i < VOCAB / 4; i += 256) {
    float4 a = base[i];
    rs += a.x + a.y + a.z + a.w;
    ss += a.x * a.x + a.y * a.y + a.z * a.z + a.w * a.w;
  }
  __shared__ float lr[4], ls[4];
  const int lane = threadIdx.x & 63, wave = threadIdx.x >> 6;
#pragma unroll
  for (int off = 32; off > 0; off >>= 1) {
    rs += __shfl_xor(rs, off);
    ss += __shfl_xor(ss, off);
  }
  if (lane == 0) { lr[wave] = rs; ls[wave] = ss; }
  __syncthreads();
  if (threadIdx.x == 0) {
    rowsum[t] = lr[0] + lr[1] + lr[2] + lr[3];
    ssum[t]   = ls[0] + ls[1] + ls[2] + ls[3];
  }
}

__global__ __launch_bounds__(512) void rl_final_old(
    const float* __restrict__ rowsum, const float* __restrict__ ssum,
    const float* __restrict__ sigma, float* __restrict__ out_RL,
    float* __restrict__ out_sigma)
{
  const int t = threadIdx.x;
  float a = ssum[t];
  float b = rowsum[t] * rowsum[t];
  __shared__ float la[8], lb[8];
  const int lane = t & 63, wave = t >> 6;
#pragma unroll
  for (int off = 32; off > 0; off >>= 1) {
    a += __shfl_xor(a, off);
    b += __shfl_xor(b, off);
  }
  if (lane == 0) { la[wave] = a; lb[wave] = b; }
  __syncthreads();
  if (t == 0) {
    float sa = 0.f, sb = 0.f;
#pragma unroll
    for (int w = 0; w < 8; ++w) { sa += la[w]; sb += lb[w]; }
    out_RL[0] = sa - sb / (float)VOCAB;
    out_sigma[0] = sigma[0];
  }
}

extern "C" void kernel_launch(void* const* d_in, const int* in_sizes, int n_in,
                              void* d_out, int out_size, void* d_ws, size_t ws_size,
                              hipStream_t stream) {
  const float* w2v   = (const float*)d_in[0];  // [50000][256]
  const float* t2v   = (const float*)d_in[1];  // [512][256]
  const float* A     = (const float*)d_in[2];  // [256][256]
  const float* B     = (const float*)d_in[3];  // [256][256]
  const float* sigma = (const float*)d_in[4];  // [1]

  float* out       = (float*)d_out;
  float* out_alpha = out;                                  // 25,600,000
  float* out_P     = out + (size_t)TOPICS * VOCAB;         // 50,000
  float* out_RL    = out_P + VOCAB;                        // 1
  float* out_s     = out_RL + 1;                           // 25,600,000
  float* out_sigma = out_s + (size_t)TOPICS * VOCAB;       // 1

  ushort* tBp = (ushort*)d_ws;                             // 262144 ushorts
  ushort* Atp = tBp + (size_t)262144;                      // 262144 ushorts
  float* tail = (float*)(Atp + (size_t)262144);            // after 1 MiB
  float* part_rs = tail;                                   // [NBLK][512]
  float* part_ss = part_rs + (size_t)NBLK * TOPICS;        // 1563*4
  float* rowsum  = part_ss + (size_t)NBLK * 4;             // 512
  size_t need = (size_t)(2 * 262144) * 2 +
                ((size_t)NBLK * TOPICS + (size_t)NBLK * 4 + TOPICS) * 4;
  const int do_rl = (ws_size >= need) ? 1 : 0;

  precompute<<<TOPICS + VDIM, 512, 0, stream>>>(t2v, A, B, tBp, Atp);

  fused_main<<<NBLK, 256, 0, stream>>>(w2v, tBp, Atp, sigma,
                                       out_alpha, out_P, out_s,
                                       part_rs, part_ss, do_rl);

  if (do_rl) {
    rl_pass2<<<16, 256, 0, stream>>>(part_rs, rowsum);
    rl_final_new<<<1, 512, 0, stream>>>(rowsum, part_ss, sigma, out_RL, out_sigma);
  } else {
    float* rs_old = tail;
    float* ss_old = rs_old + TOPICS;
    row_reduce<<<TOPICS, 256, 0, stream>>>(out_alpha, rs_old, ss_old);
    rl_final_old<<<1, 512, 0, stream>>>(rs_old, ss_old, sigma, out_RL, out_sigma);
  }
}

// Round 8
// 198.884 us; speedup vs baseline: 2.0274x; 1.2928x over previous
//
#include <hip/hip_runtime.h>

#define VOCAB 50000
#define VDIM 256
#define TOPICS 512
#define VT 32
#define NBLK 1563   // ceil(VOCAB/VT)

typedef unsigned int uint;
typedef unsigned short ushort;
using short8 = __attribute__((ext_vector_type(8))) short;
using f32x4  = __attribute__((ext_vector_type(4))) float;

__device__ __forceinline__ ushort bf16_rne(float f) {
  uint u = __float_as_uint(f);
  u += 0x7FFFu + ((u >> 16) & 1u);
  return (ushort)(u >> 16);
}
__device__ __forceinline__ float bf16f(ushort h) {
  return __uint_as_float(((uint)h) << 16);
}
__device__ __forceinline__ uint packbf2(float a, float b) {
  return (uint)bf16_rne(a) | ((uint)bf16_rne(b) << 16);
}

// ---------------------------------------------------------------------------
// Precompute with fragment-major packing (hi/lo bf16 split):
//   tBp[tile=t>>4][ks=d>>5][hl][lane=(t&15)|(((d>>3)&3)<<4)][e=d&7]
//   Atp[dtile=d>>4][ks=t>>5][hl][lane=(d&15)|(((t>>3)&3)<<4)][e=t&7]
// Each wave-load in fused_main is one coalesced 1KB dwordx4.
// ---------------------------------------------------------------------------
__global__ __launch_bounds__(512) void precompute(
    const float* __restrict__ t2v, const float* __restrict__ A,
    const float* __restrict__ B,
    ushort* __restrict__ tBp, ushort* __restrict__ Atp)
{
  __shared__ float row[256];
  const int b = blockIdx.x, tid = threadIdx.x;
  if (b < TOPICS) {
    const int t = b;
    if (tid < 256) row[tid] = t2v[(size_t)t * 256 + tid];
    __syncthreads();
    if (tid < 256) {
      const int d = tid;
      const float4* rv = (const float4*)row;
      const float4* bv = (const float4*)(B + (size_t)d * 256);
      float acc = 0.f;
#pragma unroll 8
      for (int k = 0; k < 64; ++k) {
        float4 r = rv[k], x = bv[k];
        acc += r.x * x.x + r.y * x.y + r.z * x.z + r.w * x.w;
      }
      ushort hi = bf16_rne(acc);
      ushort lo = bf16_rne(acc - bf16f(hi));
      const int tile = t >> 4, ks = d >> 5;
      const int lane = (t & 15) | (((d >> 3) & 3) << 4);
      const int e = d & 7;
      size_t base = ((size_t)(tile * 8 + ks) * 2) * 512 + lane * 8 + e;
      tBp[base]       = hi;
      tBp[base + 512] = lo;
    }
  } else {
    const int d = b - TOPICS;
    if (tid < 256) row[tid] = A[(size_t)d * 256 + tid];
    __syncthreads();
    const int t = tid;
    const float4* rv = (const float4*)row;
    const float4* tv = (const float4*)(t2v + (size_t)t * 256);
    float acc = 0.f;
#pragma unroll 8
    for (int k = 0; k < 64; ++k) {
      float4 r = rv[k], x = tv[k];
      acc += r.x * x.x + r.y * x.y + r.z * x.z + r.w * x.w;
    }
    ushort hi = bf16_rne(acc);
    ushort lo = bf16_rne(acc - bf16f(hi));
    const int dtile = d >> 4, ks = t >> 5;
    const int lane = (d & 15) | (((t >> 3) & 3) << 4);
    const int e = t & 7;
    size_t base = ((size_t)(dtile * 16 + ks) * 2) * 512 + lane * 8 + e;
    Atp[base]       = hi;
    Atp[base + 512] = lo;
  }
}

// ---------------------------------------------------------------------------
// Fused main — R3 structure (interleaved stores), with RL partials staged in
// LDS and written as ONE coalesced 2KB block store at the end (no scatter).
// ---------------------------------------------------------------------------
__global__ __launch_bounds__(256, 4) void fused_main(
    const float* __restrict__ w2v,
    const ushort* __restrict__ tBp, const ushort* __restrict__ Atp,
    const float* __restrict__ sigma,
    float* __restrict__ out_alpha, float* __restrict__ out_P,
    float* __restrict__ out_s,
    float* __restrict__ part_rs, float* __restrict__ part_ss, int do_rl)
{
  __shared__ __align__(16) char smem[33792];
  ushort (*Whi)[264] = (ushort (*)[264])smem;            // 16896 B
  ushort (*Wlo)[264] = (ushort (*)[264])(smem + 16896);  // 16896 B
  ushort (*PA)[520]  = (ushort (*)[520])smem;            // 33280 B (alias, W dead)
  __shared__ float red[4][VT];
  __shared__ float rs_lds[TOPICS];                       // 2 KB rowsum stage

  const int tid  = threadIdx.x;
  const int wave = tid >> 6, lane = tid & 63;
  const int lr = lane & 15, lg = lane >> 4;
  const int vb = blockIdx.x * VT;

  // ---- stage W hi/lo (32 rows x 256 dims) ----
#pragma unroll
  for (int it = 0; it < 8; ++it) {
    int j = tid + (it << 8);
    int v = j >> 6, q = j & 63;
    int vr = min(vb + v, VOCAB - 1);
    float4 x = *(const float4*)(w2v + (size_t)vr * 256 + (q << 2));
    float xs[4] = {x.x, x.y, x.z, x.w};
    ushort h[4], l[4];
#pragma unroll
    for (int i = 0; i < 4; ++i) {
      ushort hi = bf16_rne(xs[i]);
      h[i] = hi;
      l[i] = bf16_rne(xs[i] - bf16f(hi));
    }
    *(uint2*)&Whi[v][q << 2] = make_uint2((uint)h[0] | ((uint)h[1] << 16),
                                          (uint)h[2] | ((uint)h[3] << 16));
    *(uint2*)&Wlo[v][q << 2] = make_uint2((uint)l[0] | ((uint)l[1] << 16),
                                          (uint)l[2] | ((uint)l[3] << 16));
  }
  __syncthreads();

  // ---- s-GEMM: acc[mi][nj], t-rows = wave*128 + mi*16 + lr ----
  f32x4 acc[8][2];
#pragma unroll
  for (int mi = 0; mi < 8; ++mi)
#pragma unroll
    for (int nj = 0; nj < 2; ++nj) acc[mi][nj] = (f32x4){0.f, 0.f, 0.f, 0.f};

#pragma unroll
  for (int ks = 0; ks < 8; ++ks) {
    const int k0 = (ks << 5) + (lg << 3);
    short8 bh[2], bl[2];
#pragma unroll
    for (int nj = 0; nj < 2; ++nj) {
      bh[nj] = *(const short8*)&Whi[(nj << 4) + lr][k0];
      bl[nj] = *(const short8*)&Wlo[(nj << 4) + lr][k0];
    }
    // packed A base: tile = wave*8 + mi; stride per tile = 8192 ushorts
    const ushort* abase = tBp + ((size_t)(wave * 8) * 8 + ks) * 1024 + lane * 8;
    short8 ahp[2], alp[2];
    ahp[0] = *(const short8*)(abase);
    alp[0] = *(const short8*)(abase + 512);
    ahp[1] = *(const short8*)(abase + 8192);
    alp[1] = *(const short8*)(abase + 8192 + 512);
#pragma unroll
    for (int mi = 0; mi < 8; ++mi) {
      short8 ah = ahp[mi & 1], al = alp[mi & 1];
      if (mi < 6) {
        ahp[mi & 1] = *(const short8*)(abase + (size_t)(mi + 2) * 8192);
        alp[mi & 1] = *(const short8*)(abase + (size_t)(mi + 2) * 8192 + 512);
      }
#pragma unroll
      for (int nj = 0; nj < 2; ++nj) {
        acc[mi][nj] = __builtin_amdgcn_mfma_f32_16x16x32_bf16(ah, bh[nj], acc[mi][nj], 0, 0, 0);
        acc[mi][nj] = __builtin_amdgcn_mfma_f32_16x16x32_bf16(al, bh[nj], acc[mi][nj], 0, 0, 0);
        acc[mi][nj] = __builtin_amdgcn_mfma_f32_16x16x32_bf16(ah, bl[nj], acc[mi][nj], 0, 0, 0);
      }
    }
  }

  // ---- write s (D layout: col = lr, row = lg*4 + r) ----
#pragma unroll
  for (int mi = 0; mi < 8; ++mi) {
    const int t = (wave << 7) + (mi << 4) + (lg << 2);
#pragma unroll
    for (int r = 0; r < 4; ++r)
#pragma unroll
      for (int nj = 0; nj < 2; ++nj) {
        const int v = vb + (nj << 4) + lr;
        if (v < VOCAB) out_s[(size_t)(t + r) * VOCAB + v] = acc[mi][nj][r];
      }
  }

  // ---- softmax over t per column ----
  float gmax[2];
  {
    float pm[2] = {-3.4e38f, -3.4e38f};
#pragma unroll
    for (int mi = 0; mi < 8; ++mi)
#pragma unroll
      for (int nj = 0; nj < 2; ++nj)
#pragma unroll
        for (int r = 0; r < 4; ++r) pm[nj] = fmaxf(pm[nj], acc[mi][nj][r]);
#pragma unroll
    for (int nj = 0; nj < 2; ++nj) {
      pm[nj] = fmaxf(pm[nj], __shfl_xor(pm[nj], 16));
      pm[nj] = fmaxf(pm[nj], __shfl_xor(pm[nj], 32));
    }
    if (lg == 0) { red[wave][lr] = pm[0]; red[wave][16 + lr] = pm[1]; }
  }
  __syncthreads();
#pragma unroll
  for (int nj = 0; nj < 2; ++nj) {
    const int c = (nj << 4) + lr;
    gmax[nj] = fmaxf(fmaxf(red[0][c], red[1][c]), fmaxf(red[2][c], red[3][c]));
  }
  __syncthreads();

  float inv[2];
  {
    float ps[2] = {0.f, 0.f};
#pragma unroll
    for (int mi = 0; mi < 8; ++mi)
#pragma unroll
      for (int nj = 0; nj < 2; ++nj)
#pragma unroll
        for (int r = 0; r < 4; ++r) {
          float e = __expf(acc[mi][nj][r] - gmax[nj]);
          acc[mi][nj][r] = e;
          ps[nj] += e;
        }
#pragma unroll
    for (int nj = 0; nj < 2; ++nj) {
      ps[nj] += __shfl_xor(ps[nj], 16);
      ps[nj] += __shfl_xor(ps[nj], 32);
    }
    if (lg == 0) { red[wave][lr] = ps[0]; red[wave][16 + lr] = ps[1]; }
  }
  __syncthreads();
#pragma unroll
  for (int nj = 0; nj < 2; ++nj) {
    const int c = (nj << 4) + lr;
    inv[nj] = 1.0f / (red[0][c] + red[1][c] + red[2][c] + red[3][c]);
  }
  __syncthreads();   // red reads done; last Whi/Wlo reads were in s-loop

  // ---- alpha = exp*inv: fp32 to global, bf16 to LDS (PA aliases W),
  //      rowsum partials into rs_lds (no global scatter) ----
  float ssq = 0.f;
#pragma unroll
  for (int mi = 0; mi < 8; ++mi) {
    const int tb = (wave << 7) + (mi << 4) + (lg << 2);
#pragma unroll
    for (int nj = 0; nj < 2; ++nj) {
#pragma unroll
      for (int r = 0; r < 4; ++r) acc[mi][nj][r] *= inv[nj];
      const int v = vb + (nj << 4) + lr;
      if (v < VOCAB) {
#pragma unroll
        for (int r = 0; r < 4; ++r)
          out_alpha[(size_t)(tb + r) * VOCAB + v] = acc[mi][nj][r];
      }
      uint2 pw;
      pw.x = packbf2(acc[mi][nj][0], acc[mi][nj][1]);
      pw.y = packbf2(acc[mi][nj][2], acc[mi][nj][3]);
      *(uint2*)&PA[(nj << 4) + lr][tb] = pw;
    }
    if (do_rl) {
#pragma unroll
      for (int r = 0; r < 4; ++r) {
        float rowp = 0.f;
#pragma unroll
        for (int nj = 0; nj < 2; ++nj) {
          float a = acc[mi][nj][r];
          float am = (vb + (nj << 4) + lr < VOCAB) ? a : 0.f;
          rowp += am;
          ssq = fmaf(am, am, ssq);
        }
        rowp += __shfl_xor(rowp, 1);
        rowp += __shfl_xor(rowp, 2);
        rowp += __shfl_xor(rowp, 4);
        rowp += __shfl_xor(rowp, 8);
        if (lr == 0) rs_lds[tb + r] = rowp;
      }
    }
  }
  __syncthreads();

  // ---- mu-GEMM: macc[mi][nj], d-rows = wave*64 + mi*16 + lr, K=512 ----
  f32x4 macc[4][2];
#pragma unroll
  for (int mi = 0; mi < 4; ++mi)
#pragma unroll
    for (int nj = 0; nj < 2; ++nj) macc[mi][nj] = (f32x4){0.f, 0.f, 0.f, 0.f};

#pragma unroll
  for (int ks = 0; ks < 16; ++ks) {
    const int k0 = (ks << 5) + (lg << 3);
    short8 pb[2];
#pragma unroll
    for (int nj = 0; nj < 2; ++nj)
      pb[nj] = *(const short8*)&PA[(nj << 4) + lr][k0];
    // packed At base: dtile = wave*4 + mi; stride per dtile = 16384 ushorts
    const ushort* abase = Atp + ((size_t)(wave * 4) * 16 + ks) * 1024 + lane * 8;
    short8 ahp[2], alp[2];
    ahp[0] = *(const short8*)(abase);
    alp[0] = *(const short8*)(abase + 512);
    ahp[1] = *(const short8*)(abase + 16384);
    alp[1] = *(const short8*)(abase + 16384 + 512);
#pragma unroll
    for (int mi = 0; mi < 4; ++mi) {
      short8 ah = ahp[mi & 1], al = alp[mi & 1];
      if (mi < 2) {
        ahp[mi & 1] = *(const short8*)(abase + (size_t)(mi + 2) * 16384);
        alp[mi & 1] = *(const short8*)(abase + (size_t)(mi + 2) * 16384 + 512);
      }
#pragma unroll
      for (int nj = 0; nj < 2; ++nj) {
        macc[mi][nj] = __builtin_amdgcn_mfma_f32_16x16x32_bf16(ah, pb[nj], macc[mi][nj], 0, 0, 0);
        macc[mi][nj] = __builtin_amdgcn_mfma_f32_16x16x32_bf16(al, pb[nj], macc[mi][nj], 0, 0, 0);
      }
    }
  }

  // ---- P: sum_d (w2v - mu)^2 per column (w2v re-read from global/L2) ----
  {
    float pp[2] = {0.f, 0.f};
#pragma unroll
    for (int mi = 0; mi < 4; ++mi) {
      const int dbase = (wave << 6) + (mi << 4) + (lg << 2);
#pragma unroll
      for (int nj = 0; nj < 2; ++nj) {
        const int vr = min(vb + (nj << 4) + lr, VOCAB - 1);
        float4 w = *(const float4*)(w2v + (size_t)vr * 256 + dbase);
        float d0 = w.x - macc[mi][nj][0];
        float d1 = w.y - macc[mi][nj][1];
        float d2 = w.z - macc[mi][nj][2];
        float d3 = w.w - macc[mi][nj][3];
        pp[nj] += d0 * d0 + d1 * d1 + d2 * d2 + d3 * d3;
      }
    }
#pragma unroll
    for (int nj = 0; nj < 2; ++nj) {
      pp[nj] += __shfl_xor(pp[nj], 16);
      pp[nj] += __shfl_xor(pp[nj], 32);
    }
    if (lg == 0) { red[wave][lr] = pp[0]; red[wave][16 + lr] = pp[1]; }
  }
  __syncthreads();
  if (tid < VT) {
    float sum = red[0][tid] + red[1][tid] + red[2][tid] + red[3][tid];
    const int v = vb + tid;
    if (v < VOCAB) out_P[v] = sum / sigma[0];
  }

  // ---- coalesced part_rs block store (2KB contiguous) + ssq ----
  if (do_rl) {
    part_rs[(size_t)blockIdx.x * TOPICS + tid]       = rs_lds[tid];
    part_rs[(size_t)blockIdx.x * TOPICS + 256 + tid] = rs_lds[256 + tid];
    ssq += __shfl_xor(ssq, 1);
    ssq += __shfl_xor(ssq, 2);
    ssq += __shfl_xor(ssq, 4);
    ssq += __shfl_xor(ssq, 8);
    ssq += __shfl_xor(ssq, 16);
    ssq += __shfl_xor(ssq, 32);
    if (lane == 0) part_ss[blockIdx.x * 4 + wave] = ssq;
  }
}

// ---------------------------------------------------------------------------
// RL pass 2: rowsum[t] = sum_blk part_rs[blk][t]. One block per topic;
// 256-way ILP per block, 512 blocks -> latency fully hidden.
// ---------------------------------------------------------------------------
__global__ __launch_bounds__(256) void rl_pass2(
    const float* __restrict__ part_rs, float* __restrict__ rowsum)
{
  const int t = blockIdx.x;
  float s = 0.f;
  for (int i = threadIdx.x; i < NBLK; i += 256)
    s += part_rs[(size_t)i * TOPICS + t];
  __shared__ float lsum[4];
  const int lane = threadIdx.x & 63, wave = threadIdx.x >> 6;
#pragma unroll
  for (int off = 32; off > 0; off >>= 1) s += __shfl_xor(s, off);
  if (lane == 0) lsum[wave] = s;
  __syncthreads();
  if (threadIdx.x == 0) rowsum[t] = lsum[0] + lsum[1] + lsum[2] + lsum[3];
}

// RL finalize: RL = sum part_ss - sum_t rowsum^2 / VOCAB
__global__ __launch_bounds__(512) void rl_final_new(
    const float* __restrict__ rowsum, const float* __restrict__ part_ss,
    const float* __restrict__ sigma, float* __restrict__ out_RL,
    float* __restrict__ out_sigma)
{
  const int t = threadIdx.x;
  float b = rowsum[t] * rowsum[t];
  float a = 0.f;
  for (int i = t; i < NBLK * 4; i += 512) a += part_ss[i];
  __shared__ float la[8], lb[8];
  const int lane = t & 63, wave = t >> 6;
#pragma unroll
  for (int off = 32; off > 0; off >>= 1) {
    a += __shfl_xor(a, off);
    b += __shfl_xor(b, off);
  }
  if (lane == 0) { la[wave] = a; lb[wave] = b; }
  __syncthreads();
  if (t == 0) {
    float sa = 0.f, sb = 0.f;
#pragma unroll
    for (int w = 0; w < 8; ++w) { sa += la[w]; sb += lb[w]; }
    out_RL[0] = sa - sb / (float)VOCAB;
    out_sigma[0] = sigma[0];
  }
}

// ---------------------------------------------------------------------------
// Fallback (small ws): old alpha re-read path
// ---------------------------------------------------------------------------
__global__ __launch_bounds__(256) void row_reduce(
    const float* __restrict__ alpha, float* __restrict__ rowsum, float* __restrict__ ssum)
{
  const int t = blockIdx.x;
  const float4* base = (const float4*)(alpha + (size_t)t * VOCAB);
  float rs = 0.f, ss = 0.f;
  for (int i = threadIdx.x; i < VOCAB / 4; i += 256) {
    float4 a = base[i];
    rs += a.x + a.y + a.z + a.w;
    ss += a.x * a.x + a.y * a.y + a.z * a.z + a.w * a.w;
  }
  __shared__ float lr[4], ls[4];
  const int lane = threadIdx.x & 63, wave = threadIdx.x >> 6;
#pragma unroll
  for (int off = 32; off > 0; off >>= 1) {
    rs += __shfl_xor(rs, off);
    ss += __shfl_xor(ss, off);
  }
  if (lane == 0) { lr[wave] = rs; ls[wave] = ss; }
  __syncthreads();
  if (threadIdx.x == 0) {
    rowsum[t] = lr[0] + lr[1] + lr[2] + lr[3];
    ssum[t]   = ls[0] + ls[1] + ls[2] + ls[3];
  }
}

__global__ __launch_bounds__(512) void rl_final_old(
    const float* __restrict__ rowsum, const float* __restrict__ ssum,
    const float* __restrict__ sigma, float* __restrict__ out_RL,
    float* __restrict__ out_sigma)
{
  const int t = threadIdx.x;
  float a = ssum[t];
  float b = rowsum[t] * rowsum[t];
  __shared__ float la[8], lb[8];
  const int lane = t & 63, wave = t >> 6;
#pragma unroll
  for (int off = 32; off > 0; off >>= 1) {
    a += __shfl_xor(a, off);
    b += __shfl_xor(b, off);
  }
  if (lane == 0) { la[wave] = a; lb[wave] = b; }
  __syncthreads();
  if (t == 0) {
    float sa = 0.f, sb = 0.f;
#pragma unroll
    for (int w = 0; w < 8; ++w) { sa += la[w]; sb += lb[w]; }
    out_RL[0] = sa - sb / (float)VOCAB;
    out_sigma[0] = sigma[0];
  }
}

extern "C" void kernel_launch(void* const* d_in, const int* in_sizes, int n_in,
                              void* d_out, int out_size, void* d_ws, size_t ws_size,
                              hipStream_t stream) {
  const float* w2v   = (const float*)d_in[0];  // [50000][256]
  const float* t2v   = (const float*)d_in[1];  // [512][256]
  const float* A     = (const float*)d_in[2];  // [256][256]
  const float* B     = (const float*)d_in[3];  // [256][256]
  const float* sigma = (const float*)d_in[4];  // [1]

  float* out       = (float*)d_out;
  float* out_alpha = out;                                  // 25,600,000
  float* out_P     = out + (size_t)TOPICS * VOCAB;         // 50,000
  float* out_RL    = out_P + VOCAB;                        // 1
  float* out_s     = out_RL + 1;                           // 25,600,000
  float* out_sigma = out_s + (size_t)TOPICS * VOCAB;       // 1

  ushort* tBp = (ushort*)d_ws;                             // 262144 ushorts
  ushort* Atp = tBp + (size_t)262144;                      // 262144 ushorts
  float* tail = (float*)(Atp + (size_t)262144);            // after 1 MiB
  float* part_rs = tail;                                   // [NBLK][512]
  float* part_ss = part_rs + (size_t)NBLK * TOPICS;        // 1563*4
  float* rowsum  = part_ss + (size_t)NBLK * 4;             // 512
  size_t need = (size_t)(2 * 262144) * 2 +
                ((size_t)NBLK * TOPICS + (size_t)NBLK * 4 + TOPICS) * 4;
  const int do_rl = (ws_size >= need) ? 1 : 0;

  precompute<<<TOPICS + VDIM, 512, 0, stream>>>(t2v, A, B, tBp, Atp);

  fused_main<<<NBLK, 256, 0, stream>>>(w2v, tBp, Atp, sigma,
                                       out_alpha, out_P, out_s,
                                       part_rs, part_ss, do_rl);

  if (do_rl) {
    rl_pass2<<<TOPICS, 256, 0, stream>>>(part_rs, rowsum);
    rl_final_new<<<1, 512, 0, stream>>>(rowsum, part_ss, sigma, out_RL, out_sigma);
  } else {
    float* rs_old = tail;
    float* ss_old = rs_old + TOPICS;
    row_reduce<<<TOPICS, 256, 0, stream>>>(out_alpha, rs_old, ss_old);
    rl_final_old<<<1, 512, 0, stream>>>(rs_old, ss_old, sigma, out_RL, out_sigma);
  }
}